// Round 4
// baseline (361.942 us; speedup 1.0000x reference)
//
#include <hip/hip_runtime.h>

#define NY 512
#define NX 512
#define CC 64
#define NYNX (NY * NX)      // 262144 = 2^18
#define CPB 1024            // cells per block (gather); 262144 % 1024 == 0, no b straddle
#define CG 16               // channels per c-group
#define NCG (CC / CG)       // 4 c-groups

// ---------------- gather path (primary) ----------------

__global__ __launch_bounds__(256) void init_map_kernel(int4* __restrict__ map4, int n4) {
    int i = blockIdx.x * blockDim.x + threadIdx.x;
    if (i < n4) map4[i] = make_int4(-1, -1, -1, -1);
}

__global__ __launch_bounds__(256) void build_map_kernel(const int4* __restrict__ coords,
                                                        int* __restrict__ map, int P) {
    int p = blockIdx.x * blockDim.x + threadIdx.x;
    if (p < P) {
        int4 c = coords[p];                      // (b, z, y, x)
        int flat = c.x * NYNX + c.z * NX + c.w;  // b*NY*NX + y*NX + x
        map[flat] = p;
    }
}

// Thread = 4 consecutive cells x 16 channels, in-register 4x4 transpose.
// Stores are float4/lane (1 KB per wave-instruction); each 64B feature line
// (16 ch of one point) is fully consumed by exactly one block.
__global__ __launch_bounds__(256) void gather_t_kernel(const float4* __restrict__ feat4,
                                                       const int* __restrict__ map,
                                                       float* __restrict__ out) {
    int cb = blockIdx.x >> 2;        // cell-block index   (cgroup inner for map L2 reuse)
    int g  = blockIdx.x & (NCG - 1); // channel group
    int f0 = cb * CPB;               // first cell of block
    int b  = f0 >> 18;               // batch (constant per block)
    int r0 = f0 & (NYNX - 1);        // y*NX+x of first cell
    int fb = 4 * (int)threadIdx.x;   // this thread's cell offset within block

    // 4 cells' point indices in one coalesced int4
    int4 pi = *reinterpret_cast<const int4*>(map + f0 + fb);
    int p0 = pi.x, p1 = pi.y, p2 = pi.z, p3 = pi.w;

    // per cell: 16 channels = 4 float4 (one full 64B line), predicated on live
    float4 v0[4], v1[4], v2[4], v3[4];
#pragma unroll
    for (int k = 0; k < 4; ++k) {
        v0[k] = make_float4(0.f, 0.f, 0.f, 0.f);
        v1[k] = make_float4(0.f, 0.f, 0.f, 0.f);
        v2[k] = make_float4(0.f, 0.f, 0.f, 0.f);
        v3[k] = make_float4(0.f, 0.f, 0.f, 0.f);
    }
    if (p0 >= 0) {
        const float4* s = feat4 + (size_t)p0 * (CC / 4) + g * (CG / 4);
#pragma unroll
        for (int k = 0; k < 4; ++k) v0[k] = s[k];
    }
    if (p1 >= 0) {
        const float4* s = feat4 + (size_t)p1 * (CC / 4) + g * (CG / 4);
#pragma unroll
        for (int k = 0; k < 4; ++k) v1[k] = s[k];
    }
    if (p2 >= 0) {
        const float4* s = feat4 + (size_t)p2 * (CC / 4) + g * (CG / 4);
#pragma unroll
        for (int k = 0; k < 4; ++k) v2[k] = s[k];
    }
    if (p3 >= 0) {
        const float4* s = feat4 + (size_t)p3 * (CC / 4) + g * (CG / 4);
#pragma unroll
        for (int k = 0; k < 4; ++k) v3[k] = s[k];
    }

    // out[b][c][y][x]; channel c = g*16 + 4k + e; lane-consecutive cells -> float4
    float* obase = out + ((size_t)(b * CC + g * CG)) * NYNX + (size_t)(r0 + fb);
#pragma unroll
    for (int k = 0; k < 4; ++k) {
        float4 w;
        w = make_float4(v0[k].x, v1[k].x, v2[k].x, v3[k].x);
        *reinterpret_cast<float4*>(obase + (size_t)(4 * k + 0) * NYNX) = w;
        w = make_float4(v0[k].y, v1[k].y, v2[k].y, v3[k].y);
        *reinterpret_cast<float4*>(obase + (size_t)(4 * k + 1) * NYNX) = w;
        w = make_float4(v0[k].z, v1[k].z, v2[k].z, v3[k].z);
        *reinterpret_cast<float4*>(obase + (size_t)(4 * k + 2) * NYNX) = w;
        w = make_float4(v0[k].w, v1[k].w, v2[k].w, v3[k].w);
        *reinterpret_cast<float4*>(obase + (size_t)(4 * k + 3) * NYNX) = w;
    }
}

// ---------------- fallback path (only if ws too small) ----------------

__global__ __launch_bounds__(256) void zero_kernel(float4* __restrict__ out4, int n4) {
    int i = blockIdx.x * blockDim.x + threadIdx.x;
    if (i < n4) out4[i] = make_float4(0.f, 0.f, 0.f, 0.f);
}

__global__ __launch_bounds__(256) void scatter_kernel(const float* __restrict__ feat,
                                                      const int4* __restrict__ coords,
                                                      float* __restrict__ out, int P) {
    int idx = blockIdx.x * blockDim.x + threadIdx.x;  // p*64 + c
    int p = idx >> 6;
    int c = idx & 63;
    if (p < P) {
        int4 co = coords[p];
        out[((size_t)(co.x * CC + c)) * NYNX + (size_t)(co.z * NX + co.w)] = feat[idx];
    }
}

extern "C" void kernel_launch(void* const* d_in, const int* in_sizes, int n_in,
                              void* d_out, int out_size, void* d_ws, size_t ws_size,
                              hipStream_t stream) {
    const float* feat = (const float*)d_in[0];
    const int* coords = (const int*)d_in[1];
    int P = in_sizes[0] / CC;          // 400000
    int ncells = out_size / CC;        // B * NY * NX = 1048576
    float* out = (float*)d_out;

    if (ws_size >= (size_t)ncells * sizeof(int)) {
        int* map = (int*)d_ws;
        int n4 = ncells / 4;
        init_map_kernel<<<(n4 + 255) / 256, 256, 0, stream>>>((int4*)map, n4);
        build_map_kernel<<<(P + 255) / 256, 256, 0, stream>>>((const int4*)coords, map, P);
        int nblocks = (ncells / CPB) * NCG;   // 1024 * 4 = 4096
        gather_t_kernel<<<nblocks, 256, 0, stream>>>((const float4*)feat, map, out);
    } else {
        int n4 = out_size / 4;
        zero_kernel<<<(n4 + 255) / 256, 256, 0, stream>>>((float4*)out, n4);
        scatter_kernel<<<(P * CC + 255) / 256, 256, 0, stream>>>(feat, (const int4*)coords, out, P);
    }
}